// Round 1
// baseline (2001.144 us; speedup 1.0000x reference)
//
#include <hip/hip_runtime.h>
#include <hip/hip_bf16.h>
#include <math.h>

#define HIDC 256

// ---------------- elementwise / setup kernels ----------------

__global__ void fill_kernel(float* __restrict__ p, float v, int n) {
    int i = blockIdx.x * 256 + threadIdx.x;
    if (i < n) p[i] = v;
}

__global__ void deg_kernel(const int* __restrict__ dst, float* __restrict__ deg, int E) {
    int e = blockIdx.x * 256 + threadIdx.x;
    if (e < E) atomicAdd(&deg[dst[e]], 1.0f);
}

__global__ void rsqrt_kernel(float* __restrict__ deg, int n) {
    int i = blockIdx.x * 256 + threadIdx.x;
    if (i < n) {
        float d = deg[i];
        deg[i] = d > 0.f ? rsqrtf(d) : 0.f;
    }
}

// One block (256 threads) per edge: gather row hm[src], scale by norm, atomic-scatter to agg[dst].
__global__ void edge_agg_kernel(const float* __restrict__ hm, const int* __restrict__ src,
                                const int* __restrict__ dst, const float* __restrict__ dinv,
                                float* __restrict__ agg, int E) {
    int e = blockIdx.x;
    if (e >= E) return;
    int s = src[e], d = dst[e];
    float w = dinv[s] * dinv[d];
    int c = threadIdx.x;
    atomicAdd(&agg[(size_t)d * HIDC + c], w * hm[(size_t)s * HIDC + c]);
}

// agg[i][c] = (agg[i][c] + dinv[i]^2 * hm[i][c] + bias[c]), optional relu. In place.
// Self-loop term folded in here (norm_ii = dinv[i]^2), avoiding N*256 atomics.
__global__ void epilogue_kernel(float* __restrict__ agg, const float* __restrict__ hm,
                                const float* __restrict__ dinv, const float* __restrict__ bias,
                                int n, int do_relu) {
    int i = blockIdx.x;
    int c = threadIdx.x;
    float di = dinv[i];
    size_t idx = (size_t)i * HIDC + c;
    float v = agg[idx] + di * di * hm[idx] + bias[c];
    if (do_relu) v = fmaxf(v, 0.f);
    agg[idx] = v;
}

// alpha = sigmoid(ga + gWb + gUb); out = alpha*h_t + (1-alpha)*prev. ga may alias out.
__global__ void final_kernel(const float* __restrict__ ga, const float* __restrict__ ht,
                             const float* __restrict__ prev, const float* __restrict__ gWb,
                             const float* __restrict__ gUb, float* __restrict__ out, int n) {
    int i = blockIdx.x;
    int c = threadIdx.x;
    size_t idx = (size_t)i * HIDC + c;
    float g = ga[idx] + gWb[c] + gUb[c];
    float alpha = 1.f / (1.f + expf(-g));
    out[idx] = alpha * ht[idx] + (1.f - alpha) * prev[idx];
}

// ---------------- f32 tiled GEMM: C[M x 256] = A[M x 256] @ B[256 x 256] ----------------
// 64x64 tile, BK=16, block = 256 threads, 4x4 outputs per thread.

template <int ACC>
__global__ __launch_bounds__(256) void gemm_kernel(const float* __restrict__ A,
                                                   const float* __restrict__ B,
                                                   float* __restrict__ C, int M) {
    __shared__ __align__(16) float As[16][68];  // [k][m], pad 68: scatter writes <=2-way conflict
    __shared__ __align__(16) float Bs[16][64];  // [k][n]

    const int tl = threadIdx.x;          // 0..255
    const int tx = tl & 15;              // n quad
    const int ty = tl >> 4;              // m quad
    const int bm = blockIdx.x * 64;
    const int bn = blockIdx.y * 64;

    // A-load mapping: each thread loads one float4 of a row: m = tl/4, k-quad = tl%4
    const int am = tl >> 2;
    const int akq = tl & 3;
    // B-load mapping: k = tl/16, n-quad = tl%16 (one float4 each)
    const int bk = tl >> 4;
    const int bnq = tl & 15;

    float acc[4][4] = {};

    for (int k0 = 0; k0 < 256; k0 += 16) {
        float4 av = make_float4(0.f, 0.f, 0.f, 0.f);
        int gm = bm + am;
        if (gm < M) av = *(const float4*)(A + (size_t)gm * HIDC + k0 + akq * 4);
        As[akq * 4 + 0][am] = av.x;
        As[akq * 4 + 1][am] = av.y;
        As[akq * 4 + 2][am] = av.z;
        As[akq * 4 + 3][am] = av.w;

        float4 bv = *(const float4*)(B + (size_t)(k0 + bk) * HIDC + bn + bnq * 4);
        *(float4*)&Bs[bk][bnq * 4] = bv;

        __syncthreads();
#pragma unroll
        for (int k = 0; k < 16; k++) {
            float4 a = *(const float4*)&As[k][ty * 4];
            float4 b = *(const float4*)&Bs[k][tx * 4];
            float ar[4] = {a.x, a.y, a.z, a.w};
            float br[4] = {b.x, b.y, b.z, b.w};
#pragma unroll
            for (int i = 0; i < 4; i++)
#pragma unroll
                for (int j = 0; j < 4; j++) acc[i][j] += ar[i] * br[j];
        }
        __syncthreads();
    }

#pragma unroll
    for (int i = 0; i < 4; i++) {
        int m = bm + ty * 4 + i;
        if (m < M) {
            float4 o = make_float4(acc[i][0], acc[i][1], acc[i][2], acc[i][3]);
            float* cp = C + (size_t)m * HIDC + bn + tx * 4;
            if (ACC) {
                float4 old = *(const float4*)cp;
                o.x += old.x; o.y += old.y; o.z += old.z; o.w += old.w;
            }
            *(float4*)cp = o;
        }
    }
}

// ---------------- launch ----------------

extern "C" void kernel_launch(void* const* d_in, const int* in_sizes, int n_in,
                              void* d_out, int out_size, void* d_ws, size_t ws_size,
                              hipStream_t stream) {
    const float* x    = (const float*)d_in[0];
    const int*   ei   = (const int*)d_in[1];
    const float* prev = (const float*)d_in[2];
    const float* W1   = (const float*)d_in[3];
    const float* b1   = (const float*)d_in[4];
    const float* W2   = (const float*)d_in[5];
    const float* b2   = (const float*)d_in[6];
    const float* gWw  = (const float*)d_in[7];
    const float* gWb  = (const float*)d_in[8];
    const float* gUw  = (const float*)d_in[9];
    const float* gUb  = (const float*)d_in[10];

    const int N = in_sizes[0] / HIDC;
    const int E = in_sizes[1] / 2;
    const int* src = ei;
    const int* dst = ei + E;

    float* out  = (float*)d_out;
    float* out1 = out;                       // h_tilde region (also scratch: agg1/h, then ga)
    float* ht   = out + (size_t)N * HIDC;    // h_t region (also agg2)

    float* ws   = (float*)d_ws;
    float* dinv = ws;                                // N floats
    float* buf1 = ws + (((size_t)N + 63) / 64) * 64; // N*HIDC floats (hm1, then hm2)

    const int nhid = N * HIDC;
    const int nb_nh = (nhid + 255) / 256;
    dim3 ggrid((N + 63) / 64, HIDC / 64);

    // degree / norm
    fill_kernel<<<(N + 255) / 256, 256, 0, stream>>>(dinv, 1.0f, N);  // self-loop
    deg_kernel<<<(E + 255) / 256, 256, 0, stream>>>(dst, dinv, E);
    rsqrt_kernel<<<(N + 255) / 256, 256, 0, stream>>>(dinv, N);

    // conv1: hm1 = x@W1 -> buf1 ; agg -> out1 ; h = relu(agg + self + b1) in out1
    gemm_kernel<0><<<ggrid, 256, 0, stream>>>(x, W1, buf1, N);
    fill_kernel<<<nb_nh, 256, 0, stream>>>(out1, 0.f, nhid);
    edge_agg_kernel<<<E, 256, 0, stream>>>(buf1, src, dst, dinv, out1, E);
    epilogue_kernel<<<N, 256, 0, stream>>>(out1, buf1, dinv, b1, N, 1);

    // conv2: hm2 = h@W2 -> buf1 ; agg -> ht ; h_t = agg + self + b2 in ht
    gemm_kernel<0><<<ggrid, 256, 0, stream>>>(out1, W2, buf1, N);
    fill_kernel<<<nb_nh, 256, 0, stream>>>(ht, 0.f, nhid);
    edge_agg_kernel<<<E, 256, 0, stream>>>(buf1, src, dst, dinv, ht, E);
    epilogue_kernel<<<N, 256, 0, stream>>>(ht, buf1, dinv, b2, N, 0);

    // gate: ga = h_t@gWw + prev@gUw -> out1 ; h_tilde in place
    gemm_kernel<0><<<ggrid, 256, 0, stream>>>(ht, gWw, out1, N);
    gemm_kernel<1><<<ggrid, 256, 0, stream>>>(prev, gUw, out1, N);
    final_kernel<<<N, 256, 0, stream>>>(out1, ht, prev, gWb, gUb, out1, N);

    (void)n_in; (void)out_size; (void)ws_size;
}

// Round 2
// 900.265 us; speedup vs baseline: 2.2228x; 2.2228x over previous
//
#include <hip/hip_runtime.h>
#include <hip/hip_bf16.h>
#include <math.h>

#define HIDC 256

// ---------------- small utility kernels ----------------

__global__ void fill_i_kernel(int* __restrict__ p, int v, int n) {
    int i = blockIdx.x * 256 + threadIdx.x;
    if (i < n) p[i] = v;
}

__global__ void deg_kernel(const int* __restrict__ dst, int* __restrict__ deg, int E) {
    int e = blockIdx.x * 256 + threadIdx.x;
    if (e < E) atomicAdd(&deg[dst[e]], 1);
}

// dinv[i] = rsqrt(deg[i] + 1)   (+1 = self-loop)
__global__ void rsqrt_kernel(const int* __restrict__ deg, float* __restrict__ dinv, int n) {
    int i = blockIdx.x * 256 + threadIdx.x;
    if (i < n) dinv[i] = rsqrtf((float)(deg[i] + 1));
}

// ---------------- 3-kernel exclusive scan over degrees ----------------

__device__ __forceinline__ int block_incl_scan(int v, int tid) {
    // wave-level inclusive scan (wave64)
#pragma unroll
    for (int off = 1; off < 64; off <<= 1) {
        int t = __shfl_up(v, off);
        if ((tid & 63) >= off) v += t;
    }
    __shared__ int wt[4];
    if ((tid & 63) == 63) wt[tid >> 6] = v;
    __syncthreads();
    int wid = tid >> 6;
    for (int w = 0; w < wid; w++) v += wt[w];
    __syncthreads();
    return v;
}

__global__ void scan_a_kernel(const int* __restrict__ deg, int* __restrict__ row_start,
                              int* __restrict__ blocksum, int N) {
    int tid = threadIdx.x;
    int i = blockIdx.x * 256 + tid;
    int v = (i < N) ? deg[i] : 0;
    int incl = block_incl_scan(v, tid);
    if (i < N) row_start[i + 1] = incl;
    if (tid == 255) blocksum[blockIdx.x] = incl;
}

__global__ void scan_b_kernel(int* __restrict__ blocksum, int nb) {
    int tid = threadIdx.x;
    int v = (tid < nb) ? blocksum[tid] : 0;
    int incl = block_incl_scan(v, tid);
    if (tid < nb) blocksum[tid] = incl;
}

__global__ void scan_c_kernel(int* __restrict__ row_start, int* __restrict__ cursor,
                              const int* __restrict__ blocksum, int N) {
    int b = blockIdx.x;
    int i = b * 256 + threadIdx.x;
    int add = (b > 0) ? blocksum[b - 1] : 0;
    if (i < N) {
        int v = row_start[i + 1] + add;
        row_start[i + 1] = v;
        cursor[i + 1] = v;
    }
    if (b == 0 && threadIdx.x == 0) { row_start[0] = 0; cursor[0] = 0; }
}

// ---------------- CSR build: scatter edges into slots ----------------

__global__ void scatter_kernel(const int* __restrict__ src, const int* __restrict__ dst,
                               const float* __restrict__ dinv, int* __restrict__ cursor,
                               int* __restrict__ csr_src, float* __restrict__ csr_w, int E) {
    int e = blockIdx.x * 256 + threadIdx.x;
    if (e < E) {
        int s = src[e], d = dst[e];
        int pos = atomicAdd(&cursor[d], 1);
        csr_src[pos] = s;
        csr_w[pos] = dinv[s] * dinv[d];
    }
}

// ---------------- CSR aggregation (fused epilogue) ----------------
// One block (256 threads = 256 channels) per dst node. No atomics, single write.
// out[i][c] = act( sum_j w_j * hm[src_j][c] + dinv[i]^2 * hm[i][c] + bias[c] )

__global__ __launch_bounds__(256) void csr_agg_kernel(
    const float* __restrict__ hm, const int* __restrict__ row_start,
    const int* __restrict__ csr_src, const float* __restrict__ csr_w,
    const float* __restrict__ dinv, const float* __restrict__ bias,
    float* __restrict__ out, int do_relu) {
    __shared__ int   s_idx[64];
    __shared__ float s_w[64];
    const int i = blockIdx.x;
    const int c = threadIdx.x;
    const int b0 = row_start[i];
    const int b1 = row_start[i + 1];
    const float di = dinv[i];
    float acc = di * di * hm[(size_t)i * HIDC + c];
    for (int cb = b0; cb < b1; cb += 64) {
        int m = min(64, b1 - cb);
        if (c < m) {
            s_idx[c] = csr_src[cb + c];
            s_w[c]   = csr_w[cb + c];
        }
        __syncthreads();
        for (int t = 0; t < m; t++) {
            int s = s_idx[t];           // LDS broadcast (same addr all lanes)
            acc += s_w[t] * hm[(size_t)s * HIDC + c];
        }
        __syncthreads();
    }
    acc += bias[c];
    if (do_relu) acc = fmaxf(acc, 0.f);
    out[(size_t)i * HIDC + c] = acc;
}

// alpha = sigmoid(ga + gWb + gUb); out = alpha*h_t + (1-alpha)*prev. ga may alias out.
__global__ void final_kernel(const float* __restrict__ ga, const float* __restrict__ ht,
                             const float* __restrict__ prev, const float* __restrict__ gWb,
                             const float* __restrict__ gUb, float* __restrict__ out, int n) {
    int i = blockIdx.x;
    int c = threadIdx.x;
    size_t idx = (size_t)i * HIDC + c;
    float g = ga[idx] + gWb[c] + gUb[c];
    float alpha = 1.f / (1.f + expf(-g));
    out[idx] = alpha * ht[idx] + (1.f - alpha) * prev[idx];
}

// ---------------- f32 tiled GEMM: C[M x 256] = A[M x 256] @ B[256 x 256] ----------------

template <int ACC>
__global__ __launch_bounds__(256) void gemm_kernel(const float* __restrict__ A,
                                                   const float* __restrict__ B,
                                                   float* __restrict__ C, int M) {
    __shared__ __align__(16) float As[16][68];
    __shared__ __align__(16) float Bs[16][64];

    const int tl = threadIdx.x;
    const int tx = tl & 15;
    const int ty = tl >> 4;
    const int bm = blockIdx.x * 64;
    const int bn = blockIdx.y * 64;

    const int am = tl >> 2;
    const int akq = tl & 3;
    const int bk = tl >> 4;
    const int bnq = tl & 15;

    float acc[4][4] = {};

    for (int k0 = 0; k0 < 256; k0 += 16) {
        float4 av = make_float4(0.f, 0.f, 0.f, 0.f);
        int gm = bm + am;
        if (gm < M) av = *(const float4*)(A + (size_t)gm * HIDC + k0 + akq * 4);
        As[akq * 4 + 0][am] = av.x;
        As[akq * 4 + 1][am] = av.y;
        As[akq * 4 + 2][am] = av.z;
        As[akq * 4 + 3][am] = av.w;

        float4 bv = *(const float4*)(B + (size_t)(k0 + bk) * HIDC + bn + bnq * 4);
        *(float4*)&Bs[bk][bnq * 4] = bv;

        __syncthreads();
#pragma unroll
        for (int k = 0; k < 16; k++) {
            float4 a = *(const float4*)&As[k][ty * 4];
            float4 b = *(const float4*)&Bs[k][tx * 4];
            float ar[4] = {a.x, a.y, a.z, a.w};
            float br[4] = {b.x, b.y, b.z, b.w};
#pragma unroll
            for (int i = 0; i < 4; i++)
#pragma unroll
                for (int j = 0; j < 4; j++) acc[i][j] += ar[i] * br[j];
        }
        __syncthreads();
    }

#pragma unroll
    for (int i = 0; i < 4; i++) {
        int m = bm + ty * 4 + i;
        if (m < M) {
            float4 o = make_float4(acc[i][0], acc[i][1], acc[i][2], acc[i][3]);
            float* cp = C + (size_t)m * HIDC + bn + tx * 4;
            if (ACC) {
                float4 old = *(const float4*)cp;
                o.x += old.x; o.y += old.y; o.z += old.z; o.w += old.w;
            }
            *(float4*)cp = o;
        }
    }
}

// ---------------- launch ----------------

extern "C" void kernel_launch(void* const* d_in, const int* in_sizes, int n_in,
                              void* d_out, int out_size, void* d_ws, size_t ws_size,
                              hipStream_t stream) {
    const float* x    = (const float*)d_in[0];
    const int*   ei   = (const int*)d_in[1];
    const float* prev = (const float*)d_in[2];
    const float* W1   = (const float*)d_in[3];
    const float* b1   = (const float*)d_in[4];
    const float* W2   = (const float*)d_in[5];
    const float* b2   = (const float*)d_in[6];
    const float* gWw  = (const float*)d_in[7];
    const float* gWb  = (const float*)d_in[8];
    const float* gUw  = (const float*)d_in[9];
    const float* gUb  = (const float*)d_in[10];

    const int N = in_sizes[0] / HIDC;
    const int E = in_sizes[1] / 2;
    const int* src = ei;
    const int* dst = ei + E;

    float* out  = (float*)d_out;
    float* out1 = out;                       // h_tilde region (scratch: h, then ga)
    float* ht   = out + (size_t)N * HIDC;    // h_t region

    // workspace layout (all 4-byte elems)
    float* ws      = (float*)d_ws;
    float* dinv    = ws;                           // N
    int*   degi    = (int*)(ws + N);               // N
    int*   row_st  = (int*)(ws + 2 * (size_t)N);   // N+1
    int*   cursor  = row_st + (N + 1);             // N+1
    int*   csr_src = cursor + (N + 1);             // E
    float* csr_w   = (float*)(csr_src + E);        // E
    size_t buf_off = ((4 * (size_t)N + 2 + 2 * (size_t)E) + 63) & ~(size_t)63;
    float* buf1    = ws + buf_off;                 // N * HIDC

    const int nbN = (N + 255) / 256;
    const int nbE = (E + 255) / 256;
    dim3 ggrid((N + 63) / 64, HIDC / 64);

    // ---- CSR build ----
    fill_i_kernel<<<nbN, 256, 0, stream>>>(degi, 0, N);
    deg_kernel<<<nbE, 256, 0, stream>>>(dst, degi, E);
    scan_a_kernel<<<nbN, 256, 0, stream>>>(degi, row_st, cursor /*reuse as blocksum? no*/, N);
    // NOTE: blocksum needs its own space; reuse tail of cursor is unsafe. Use degi tail?
    // Simpler: blocksum stored in degi (degi is dead after scan_a reads it? scan_a reads deg
    // while writing blocksum — must not alias). Use a dedicated small region: end of csr_w
    // is free until scatter. Place blocksum at csr_w (floats area, as ints) — dead until scatter.
    // Relaunch properly below.
    // (The scan_a above already ran with 'cursor' as blocksum — overwritten correctly below.)
    int* blocksum = (int*)csr_w;  // free until scatter_kernel
    scan_a_kernel<<<nbN, 256, 0, stream>>>(degi, row_st, blocksum, N);
    scan_b_kernel<<<1, 256, 0, stream>>>(blocksum, nbN);
    scan_c_kernel<<<nbN, 256, 0, stream>>>(row_st, cursor, blocksum, N);
    rsqrt_kernel<<<nbN, 256, 0, stream>>>(degi, dinv, N);
    scatter_kernel<<<nbE, 256, 0, stream>>>(src, dst, dinv, cursor, csr_src, csr_w, E);

    // ---- conv1: hm1 = x@W1 ; h = relu(agg + self + b1) -> out1 ----
    gemm_kernel<0><<<ggrid, 256, 0, stream>>>(x, W1, buf1, N);
    csr_agg_kernel<<<N, 256, 0, stream>>>(buf1, row_st, csr_src, csr_w, dinv, b1, out1, 1);

    // ---- conv2: hm2 = h@W2 ; h_t = agg + self + b2 -> ht ----
    gemm_kernel<0><<<ggrid, 256, 0, stream>>>(out1, W2, buf1, N);
    csr_agg_kernel<<<N, 256, 0, stream>>>(buf1, row_st, csr_src, csr_w, dinv, b2, ht, 0);

    // ---- gate ----
    gemm_kernel<0><<<ggrid, 256, 0, stream>>>(ht, gWw, out1, N);
    gemm_kernel<1><<<ggrid, 256, 0, stream>>>(prev, gUw, out1, N);
    final_kernel<<<N, 256, 0, stream>>>(out1, ht, prev, gWb, gUb, out1, N);

    (void)n_in; (void)out_size; (void)ws_size;
}

// Round 3
// 608.478 us; speedup vs baseline: 3.2888x; 1.4795x over previous
//
#include <hip/hip_runtime.h>
#include <hip/hip_bf16.h>
#include <math.h>

#define HIDC 256
#define LSTR 56   // LDS row stride in ushorts: 112 B = 16B-aligned, 2-way-conflict-free (free per m136)

typedef short short8 __attribute__((ext_vector_type(8)));
typedef float f32x4 __attribute__((ext_vector_type(4)));

__device__ __forceinline__ ushort f2bf_rne(float f) {
    uint u = __float_as_uint(f);
    u += 0x7FFF + ((u >> 16) & 1);
    return (ushort)(u >> 16);
}
__device__ __forceinline__ float bf2f(ushort h) {
    return __uint_as_float(((uint)h) << 16);
}

// ---------------- small utility kernels ----------------

__global__ void fill_i_kernel(int* __restrict__ p, int v, int n) {
    int i = blockIdx.x * 256 + threadIdx.x;
    if (i < n) p[i] = v;
}

__global__ void deg_kernel(const int* __restrict__ dst, int* __restrict__ deg, int E) {
    int e = blockIdx.x * 256 + threadIdx.x;
    if (e < E) atomicAdd(&deg[dst[e]], 1);
}

__global__ void rsqrt_kernel(const int* __restrict__ deg, float* __restrict__ dinv, int n) {
    int i = blockIdx.x * 256 + threadIdx.x;
    if (i < n) dinv[i] = rsqrtf((float)(deg[i] + 1));   // +1 = self-loop
}

// ---------------- 3-kernel exclusive scan ----------------

__device__ __forceinline__ int block_incl_scan(int v, int tid) {
#pragma unroll
    for (int off = 1; off < 64; off <<= 1) {
        int t = __shfl_up(v, off);
        if ((tid & 63) >= off) v += t;
    }
    __shared__ int wt[4];
    if ((tid & 63) == 63) wt[tid >> 6] = v;
    __syncthreads();
    int wid = tid >> 6;
    for (int w = 0; w < wid; w++) v += wt[w];
    __syncthreads();
    return v;
}

__global__ void scan_a_kernel(const int* __restrict__ deg, int* __restrict__ row_start,
                              int* __restrict__ blocksum, int N) {
    int tid = threadIdx.x;
    int i = blockIdx.x * 256 + tid;
    int v = (i < N) ? deg[i] : 0;
    int incl = block_incl_scan(v, tid);
    if (i < N) row_start[i + 1] = incl;
    if (tid == 255) blocksum[blockIdx.x] = incl;
}

__global__ void scan_b_kernel(int* __restrict__ blocksum, int nb) {
    int tid = threadIdx.x;
    int v = (tid < nb) ? blocksum[tid] : 0;
    int incl = block_incl_scan(v, tid);
    if (tid < nb) blocksum[tid] = incl;
}

__global__ void scan_c_kernel(int* __restrict__ row_start, int* __restrict__ cursor,
                              const int* __restrict__ blocksum, int N) {
    int b = blockIdx.x;
    int i = b * 256 + threadIdx.x;
    int add = (b > 0) ? blocksum[b - 1] : 0;
    if (i < N) {
        int v = row_start[i + 1] + add;
        row_start[i + 1] = v;
        cursor[i + 1] = v;
    }
    if (b == 0 && threadIdx.x == 0) { row_start[0] = 0; cursor[0] = 0; }
}

__global__ void scatter_kernel(const int* __restrict__ src, const int* __restrict__ dst,
                               const float* __restrict__ dinv, int* __restrict__ cursor,
                               int* __restrict__ csr_src, float* __restrict__ csr_w, int E) {
    int e = blockIdx.x * 256 + threadIdx.x;
    if (e < E) {
        int s = src[e], d = dst[e];
        int pos = atomicAdd(&cursor[d], 1);
        csr_src[pos] = s;
        csr_w[pos] = dinv[s] * dinv[d];
    }
}

// ---------------- weight prep: Bt[n][k] = bf16(B[k][n]) ----------------

__global__ void prep_bt_kernel(const float* __restrict__ B, ushort* __restrict__ Bt) {
    int n = blockIdx.x, k = threadIdx.x;
    Bt[n * 256 + k] = f2bf_rne(B[k * 256 + n]);
}

// combined gate weights: rows 0..255 <- gWw, 256..511 <- gUw, hi/lo split, [n][512k]
__global__ void prep_gate_bt_kernel(const float* __restrict__ gWw, const float* __restrict__ gUw,
                                    ushort* __restrict__ Bth, ushort* __restrict__ Btl) {
    int n = blockIdx.x, k = threadIdx.x;
    float v1 = gWw[k * 256 + n];
    uint u1 = __float_as_uint(v1);
    Bth[n * 512 + k] = (ushort)(u1 >> 16);
    Btl[n * 512 + k] = f2bf_rne(v1 - __uint_as_float(u1 & 0xFFFF0000u));
    float v2 = gUw[k * 256 + n];
    uint u2 = __float_as_uint(v2);
    Bth[n * 512 + 256 + k] = (ushort)(u2 >> 16);
    Btl[n * 512 + 256 + k] = f2bf_rne(v2 - __uint_as_float(u2 & 0xFFFF0000u));
}

// ---------------- MFMA GEMM (single-pass bf16): C_bf16[Mx256] = A_f32[Mx256] @ B ----------------
// 128x128 tile, BK=32, 256 thr (2x2 waves of 64x64), 16x16x32 MFMA.

__global__ __launch_bounds__(256) void gemm_bf16_kernel(
    const float* __restrict__ A, const ushort* __restrict__ Bt,  // Bt: [256n][256k] bf16
    ushort* __restrict__ C, int M)
{
    __shared__ __align__(16) ushort As[128 * LSTR];
    __shared__ __align__(16) ushort Bs[128 * LSTR];
    const int tl = threadIdx.x;
    const int lane = tl & 63, wave = tl >> 6;
    const int wm = (wave & 1) * 64, wn = (wave >> 1) * 64;
    const int bm = blockIdx.x * 128, bn = blockIdx.y * 128;

    const int ar  = tl >> 1;          // A stage row
    const int akq = (tl & 1) * 16;    // A stage k base (16 floats)
    const bool aok = (bm + ar) < M;

    f32x4 acc[4][4] = {};

    for (int k0 = 0; k0 < 256; k0 += 32) {
        {   // A stage: f32 -> bf16 RNE
            const float* ap = A + (size_t)(bm + ar) * HIDC + k0 + akq;
#pragma unroll
            for (int j = 0; j < 4; j++) {
                float4 v = aok ? *(const float4*)(ap + 4 * j) : make_float4(0.f, 0.f, 0.f, 0.f);
                ushort4 h;
                h.x = f2bf_rne(v.x); h.y = f2bf_rne(v.y);
                h.z = f2bf_rne(v.z); h.w = f2bf_rne(v.w);
                *(ushort4*)&As[ar * LSTR + akq + 4 * j] = h;
            }
        }
        {   // B stage: copy 32 B
            const ushort* bp = Bt + (size_t)(bn + ar) * 256 + k0 + akq;
            *(uint4*)&Bs[ar * LSTR + akq]     = *(const uint4*)bp;
            *(uint4*)&Bs[ar * LSTR + akq + 8] = *(const uint4*)(bp + 8);
        }
        __syncthreads();
        const int fr = lane & 15, koff = (lane >> 4) * 8;
        short8 af[4], bfv[4];
#pragma unroll
        for (int t = 0; t < 4; t++) {
            af[t]  = *(const short8*)&As[(wm + t * 16 + fr) * LSTR + koff];
            bfv[t] = *(const short8*)&Bs[(wn + t * 16 + fr) * LSTR + koff];
        }
#pragma unroll
        for (int mt = 0; mt < 4; mt++)
#pragma unroll
            for (int nt = 0; nt < 4; nt++)
                acc[mt][nt] = __builtin_amdgcn_mfma_f32_16x16x32_bf16(af[mt], bfv[nt], acc[mt][nt], 0, 0, 0);
        __syncthreads();
    }

    // epilogue: C/D layout col=lane&15, row=(lane>>4)*4+reg  [m89-verified]
    const int row4 = (lane >> 4) * 4, coln = lane & 15;
#pragma unroll
    for (int mt = 0; mt < 4; mt++)
#pragma unroll
        for (int r = 0; r < 4; r++) {
            int m = bm + wm + mt * 16 + row4 + r;
            if (m < M) {
#pragma unroll
                for (int nt = 0; nt < 4; nt++) {
                    int n = bn + wn + nt * 16 + coln;
                    C[(size_t)m * HIDC + n] = f2bf_rne(acc[mt][nt][r]);
                }
            }
        }
}

// ---------------- gate GEMM: split hi/lo bf16, K=512 concat(ht,prev), fused sigmoid blend ----------------

__global__ __launch_bounds__(256) void gate_kernel(
    const float* __restrict__ ht, const float* __restrict__ prev,
    const ushort* __restrict__ Bth, const ushort* __restrict__ Btl,  // [256n][512k]
    const float* __restrict__ gWb, const float* __restrict__ gUb,
    float* __restrict__ out, int M)
{
    __shared__ __align__(16) ushort Ash[128 * LSTR];
    __shared__ __align__(16) ushort Asl[128 * LSTR];
    __shared__ __align__(16) ushort Bsh[128 * LSTR];
    __shared__ __align__(16) ushort Bsl[128 * LSTR];
    const int tl = threadIdx.x;
    const int lane = tl & 63, wave = tl >> 6;
    const int wm = (wave & 1) * 64, wn = (wave >> 1) * 64;
    const int bm = blockIdx.x * 128, bn = blockIdx.y * 128;

    const int ar  = tl >> 1;
    const int akq = (tl & 1) * 16;
    const bool aok = (bm + ar) < M;

    f32x4 acc[4][4] = {};

    for (int k0 = 0; k0 < 512; k0 += 32) {
        {   // A stage: hi/lo split from ht (k<256) or prev
            const float* srcA = (k0 < 256) ? ht : prev;
            const float* ap = srcA + (size_t)(bm + ar) * HIDC + (k0 & 255) + akq;
#pragma unroll
            for (int j = 0; j < 4; j++) {
                float4 v = aok ? *(const float4*)(ap + 4 * j) : make_float4(0.f, 0.f, 0.f, 0.f);
                float vv[4] = {v.x, v.y, v.z, v.w};
                ushort4 hh, ll;
                ushort* hp = (ushort*)&hh; ushort* lp = (ushort*)&ll;
#pragma unroll
                for (int q = 0; q < 4; q++) {
                    uint u = __float_as_uint(vv[q]);
                    hp[q] = (ushort)(u >> 16);
                    lp[q] = f2bf_rne(vv[q] - __uint_as_float(u & 0xFFFF0000u));
                }
                *(ushort4*)&Ash[ar * LSTR + akq + 4 * j] = hh;
                *(ushort4*)&Asl[ar * LSTR + akq + 4 * j] = ll;
            }
        }
        {   // B stage
            const ushort* bph = Bth + (size_t)(bn + ar) * 512 + k0 + akq;
            const ushort* bpl = Btl + (size_t)(bn + ar) * 512 + k0 + akq;
            *(uint4*)&Bsh[ar * LSTR + akq]     = *(const uint4*)bph;
            *(uint4*)&Bsh[ar * LSTR + akq + 8] = *(const uint4*)(bph + 8);
            *(uint4*)&Bsl[ar * LSTR + akq]     = *(const uint4*)bpl;
            *(uint4*)&Bsl[ar * LSTR + akq + 8] = *(const uint4*)(bpl + 8);
        }
        __syncthreads();
        const int fr = lane & 15, koff = (lane >> 4) * 8;
        short8 afh[4], afl[4], bfh[4], bfl[4];
#pragma unroll
        for (int t = 0; t < 4; t++) {
            afh[t] = *(const short8*)&Ash[(wm + t * 16 + fr) * LSTR + koff];
            afl[t] = *(const short8*)&Asl[(wm + t * 16 + fr) * LSTR + koff];
            bfh[t] = *(const short8*)&Bsh[(wn + t * 16 + fr) * LSTR + koff];
            bfl[t] = *(const short8*)&Bsl[(wn + t * 16 + fr) * LSTR + koff];
        }
#pragma unroll
        for (int mt = 0; mt < 4; mt++)
#pragma unroll
            for (int nt = 0; nt < 4; nt++) {
                acc[mt][nt] = __builtin_amdgcn_mfma_f32_16x16x32_bf16(afh[mt], bfh[nt], acc[mt][nt], 0, 0, 0);
                acc[mt][nt] = __builtin_amdgcn_mfma_f32_16x16x32_bf16(afh[mt], bfl[nt], acc[mt][nt], 0, 0, 0);
                acc[mt][nt] = __builtin_amdgcn_mfma_f32_16x16x32_bf16(afl[mt], bfh[nt], acc[mt][nt], 0, 0, 0);
            }
        __syncthreads();
    }

    const int row4 = (lane >> 4) * 4, coln = lane & 15;
#pragma unroll
    for (int mt = 0; mt < 4; mt++)
#pragma unroll
        for (int r = 0; r < 4; r++) {
            int m = bm + wm + mt * 16 + row4 + r;
            if (m < M) {
#pragma unroll
                for (int nt = 0; nt < 4; nt++) {
                    int n = bn + wn + nt * 16 + coln;
                    size_t idx = (size_t)m * HIDC + n;
                    float g = acc[mt][nt][r] + gWb[n] + gUb[n];
                    float alpha = 1.f / (1.f + expf(-g));
                    out[idx] = alpha * ht[idx] + (1.f - alpha) * prev[idx];
                }
            }
        }
}

// ---------------- CSR aggregation over bf16 hm, f32 out, fused bias/relu/self-loop ----------------

__global__ __launch_bounds__(256) void csr_agg_kernel(
    const ushort* __restrict__ hm, const int* __restrict__ row_start,
    const int* __restrict__ csr_src, const float* __restrict__ csr_w,
    const float* __restrict__ dinv, const float* __restrict__ bias,
    float* __restrict__ out, int do_relu) {
    __shared__ int   s_idx[64];
    __shared__ float s_w[64];
    const int i = blockIdx.x;
    const int c = threadIdx.x;
    const int b0 = row_start[i];
    const int b1 = row_start[i + 1];
    const float di = dinv[i];
    float acc = di * di * bf2f(hm[(size_t)i * HIDC + c]);
    for (int cb = b0; cb < b1; cb += 64) {
        int m = min(64, b1 - cb);
        if (c < m) {
            s_idx[c] = csr_src[cb + c];
            s_w[c]   = csr_w[cb + c];
        }
        __syncthreads();
        for (int t = 0; t < m; t++) {
            int s = s_idx[t];
            acc += s_w[t] * bf2f(hm[(size_t)s * HIDC + c]);
        }
        __syncthreads();
    }
    acc += bias[c];
    if (do_relu) acc = fmaxf(acc, 0.f);
    out[(size_t)i * HIDC + c] = acc;
}

// ---------------- launch ----------------

extern "C" void kernel_launch(void* const* d_in, const int* in_sizes, int n_in,
                              void* d_out, int out_size, void* d_ws, size_t ws_size,
                              hipStream_t stream) {
    const float* x    = (const float*)d_in[0];
    const int*   ei   = (const int*)d_in[1];
    const float* prev = (const float*)d_in[2];
    const float* W1   = (const float*)d_in[3];
    const float* b1   = (const float*)d_in[4];
    const float* W2   = (const float*)d_in[5];
    const float* b2   = (const float*)d_in[6];
    const float* gWw  = (const float*)d_in[7];
    const float* gWb  = (const float*)d_in[8];
    const float* gUw  = (const float*)d_in[9];
    const float* gUb  = (const float*)d_in[10];

    const int N = in_sizes[0] / HIDC;
    const int E = in_sizes[1] / 2;
    const int* src = ei;
    const int* dst = ei + E;

    float* out  = (float*)d_out;
    float* out1 = out;                       // h_tilde region (scratch: h f32)
    float* ht   = out + (size_t)N * HIDC;    // h_t region (f32)

    // workspace layout (float units, 64-aligned chunks)
    float* ws = (float*)d_ws;
    size_t o = 0;
    auto take = [&](size_t n) { size_t r = o; o += (n + 63) & ~(size_t)63; return r; };
    float*  dinv    = ws + take(N);
    int*    degi    = (int*)(ws + take(N));
    int*    row_st  = (int*)(ws + take(N + 1));
    int*    cursor  = (int*)(ws + take(N + 1));
    int*    csr_src = (int*)(ws + take(E));
    float*  csr_w   = ws + take(E);
    ushort* Bt1     = (ushort*)(ws + take(256 * 256 / 2));
    ushort* Bt2     = (ushort*)(ws + take(256 * 256 / 2));
    ushort* Bth     = (ushort*)(ws + take(256 * 512 / 2));
    ushort* Btl     = (ushort*)(ws + take(256 * 512 / 2));
    ushort* hm      = (ushort*)(ws + take((size_t)N * HIDC / 2));

    const int nbN = (N + 255) / 256;
    const int nbE = (E + 255) / 256;
    dim3 ggrid((N + 127) / 128, 2);

    // ---- CSR build ----
    int* blocksum = (int*)csr_w;  // free until scatter_kernel
    fill_i_kernel<<<nbN, 256, 0, stream>>>(degi, 0, N);
    deg_kernel<<<nbE, 256, 0, stream>>>(dst, degi, E);
    scan_a_kernel<<<nbN, 256, 0, stream>>>(degi, row_st, blocksum, N);
    scan_b_kernel<<<1, 256, 0, stream>>>(blocksum, nbN);
    scan_c_kernel<<<nbN, 256, 0, stream>>>(row_st, cursor, blocksum, N);
    rsqrt_kernel<<<nbN, 256, 0, stream>>>(degi, dinv, N);
    scatter_kernel<<<nbE, 256, 0, stream>>>(src, dst, dinv, cursor, csr_src, csr_w, E);

    // ---- weight prep ----
    prep_bt_kernel<<<256, 256, 0, stream>>>(W1, Bt1);
    prep_bt_kernel<<<256, 256, 0, stream>>>(W2, Bt2);
    prep_gate_bt_kernel<<<256, 256, 0, stream>>>(gWw, gUw, Bth, Btl);

    // ---- conv1 ----
    gemm_bf16_kernel<<<ggrid, 256, 0, stream>>>(x, Bt1, hm, N);
    csr_agg_kernel<<<N, 256, 0, stream>>>(hm, row_st, csr_src, csr_w, dinv, b1, out1, 1);

    // ---- conv2 ----
    gemm_bf16_kernel<<<ggrid, 256, 0, stream>>>(out1, Bt2, hm, N);
    csr_agg_kernel<<<N, 256, 0, stream>>>(hm, row_st, csr_src, csr_w, dinv, b2, ht, 0);

    // ---- gate (fused final) ----
    gate_kernel<<<ggrid, 256, 0, stream>>>(ht, prev, Bth, Btl, gWb, gUb, out1, N);

    (void)n_in; (void)out_size; (void)ws_size;
}